// Round 8
// baseline (960.510 us; speedup 1.0000x reference)
//
#include <hip/hip_runtime.h>

#define KNN 16
#define FSEM 32
#define LPG 4                 // 4 lanes cooperate per gaussian
#define HDR 256               // ints reserved at head of ws for counters

__device__ __forceinline__ float sigmoidf_(float x) { return 1.0f / (1.0f + __expf(-x)); }

// q / clip(|q|,1e-12) -> row-major 3x3
__device__ __forceinline__ void quat_to_R(float qw, float qx, float qy, float qz, float* R) {
    float d = qw * qw + qx * qx + qy * qy + qz * qz;
    float inv = rsqrtf(fmaxf(d, 1e-24f));
    float w = qw * inv, x = qx * inv, y = qy * inv, z = qz * inv;
    R[0] = 1.f - 2.f * (y * y + z * z); R[1] = 2.f * (x * y - w * z); R[2] = 2.f * (x * z + w * y);
    R[3] = 2.f * (x * y + w * z); R[4] = 1.f - 2.f * (x * x + z * z); R[5] = 2.f * (y * z - w * x);
    R[6] = 2.f * (x * z - w * y); R[7] = 2.f * (y * z + w * x); R[8] = 1.f - 2.f * (x * x + y * y);
}

// ---- bucketing pipeline: counting-sort gaussian ids by ref_time into perm ----
__global__ void k_zero(int* __restrict__ hdr) {
    if (threadIdx.x < HDR) hdr[threadIdx.x] = 0;
}
__global__ void k_hist(const int* __restrict__ ref_time, int* __restrict__ cnt, int N) {
    int n = blockIdx.x * blockDim.x + threadIdx.x;
    if (n < N) atomicAdd(&cnt[ref_time[n]], 1);
}
__global__ void k_prefix(int* __restrict__ hdr, int T) {
    // hdr[0..T): counts -> exclusive base; hdr[128..128+T): running cursor copy
    if (threadIdx.x == 0 && blockIdx.x == 0) {
        int run = 0;
        for (int r = 0; r < T; r++) {
            int c = hdr[r];
            hdr[r] = run;
            hdr[128 + r] = run;
            run += c;
        }
    }
}
__global__ void k_scatter(const int* __restrict__ ref_time, int* __restrict__ hdr,
                          int* __restrict__ perm, int N) {
    int n = blockIdx.x * blockDim.x + threadIdx.x;
    if (n < N) {
        int pos = atomicAdd(&hdr[128 + ref_time[n]], 1);
        perm[pos] = n;
    }
}

// ---- elementwise outputs in natural (coalesced) order: s, o, sph ----
__global__ void __launch_bounds__(256)
k_elem(const float* __restrict__ gs_scal,
       const float* __restrict__ gs_opa,
       const float* __restrict__ feat_dc,
       const float* __restrict__ feat_rest,
       float* __restrict__ out, int N)
{
    const int n = blockIdx.x * blockDim.x + threadIdx.x;
    if (n >= N) return;
    const size_t Ns = (size_t)N, ns = (size_t)n;

    float* os = out + 12 * Ns + 3 * ns;
    os[0] = 0.1f * sigmoidf_(gs_scal[3 * ns + 0]);
    os[1] = 0.1f * sigmoidf_(gs_scal[3 * ns + 1]);
    os[2] = 0.1f * sigmoidf_(gs_scal[3 * ns + 2]);

    out[15 * Ns + ns] = sigmoidf_(gs_opa[ns]);

    float* osph = out + 16 * Ns + 12 * ns;   // 16B-aligned
    float4 v0 = make_float4(feat_dc[3 * ns + 0], feat_dc[3 * ns + 1], feat_dc[3 * ns + 2],
                            feat_rest[9 * ns + 0]);
    float4 v1 = make_float4(feat_rest[9 * ns + 1], feat_rest[9 * ns + 2],
                            feat_rest[9 * ns + 3], feat_rest[9 * ns + 4]);
    float4 v2 = make_float4(feat_rest[9 * ns + 5], feat_rest[9 * ns + 6],
                            feat_rest[9 * ns + 7], feat_rest[9 * ns + 8]);
    reinterpret_cast<float4*>(osph)[0] = v0;
    reinterpret_cast<float4*>(osph)[1] = v1;
    reinterpret_cast<float4*>(osph)[2] = v2;
}

// ---- main skinning kernel; PERM selects bucket order (or identity fallback) ----
template<bool PERM>
__global__ void __launch_bounds__(256)
dynscf_kernel(const float* __restrict__ gs_xyz,
              const float* __restrict__ gs_rot,
              const float* __restrict__ node_xyz,
              const float* __restrict__ node_quat,
              const float* __restrict__ node_sigma,
              const float* __restrict__ node_sem,
              const int* __restrict__ attach_ind,
              const int* __restrict__ ref_time,
              const int* __restrict__ topo_knn,
              const int* __restrict__ t_ptr,
              const int* __restrict__ perm,
              float* __restrict__ out,
              int N, int M)
{
    const int tid = blockIdx.x * blockDim.x + threadIdx.x;
    const int gi  = tid >> 2;
    const int sub = tid & (LPG - 1);
    if (gi >= N) return;
    const int n = PERM ? perm[gi] : gi;

    const int t  = t_ptr[0];
    const int a  = attach_ind[n];
    const int rt = ref_time[n];

    const size_t base_rt = (size_t)rt * (size_t)M;
    const size_t base_t  = (size_t)t  * (size_t)M;

    const float4 qa = *reinterpret_cast<const float4*>(node_quat + (base_rt + (size_t)a) * 4);
    float Rref[9];
    quat_to_R(qa.x, qa.y, qa.z, qa.w, Rref);

    const float* pa = node_xyz + (base_rt + (size_t)a) * 3;
    const float px = pa[0], py = pa[1], pz = pa[2];

    const float gx = gs_xyz[3 * (size_t)n + 0];
    const float gy = gs_xyz[3 * (size_t)n + 1];
    const float gz = gs_xyz[3 * (size_t)n + 2];

    const float xw0 = Rref[0] * gx + Rref[1] * gy + Rref[2] * gz + px;
    const float xw1 = Rref[3] * gx + Rref[4] * gy + Rref[5] * gz + py;
    const float xw2 = Rref[6] * gx + Rref[7] * gy + Rref[8] * gz + pz;

    const int4 kv = reinterpret_cast<const int4*>(topo_knn)[(size_t)a * (KNN / 4) + sub];
    const int js[4] = { kv.x, kv.y, kv.z, kv.w };

    float wsum = 0.f, mu0 = 0.f, mu1 = 0.f, mu2 = 0.f;
    float qb0 = 0.f, qb1 = 0.f, qb2 = 0.f, qb3 = 0.f;
    float sem[FSEM];
#pragma unroll
    for (int f = 0; f < FSEM; f++) sem[f] = 0.f;

#pragma unroll
    for (int k = 0; k < KNN / LPG; k++) {
        const int j = js[k];

        const float* pr = node_xyz + (base_rt + (size_t)j) * 3;
        const float dx = xw0 - pr[0];
        const float dy = xw1 - pr[1];
        const float dz = xw2 - pr[2];
        const float dsq = dx * dx + dy * dy + dz * dz;

        const float sg = node_sigma[j];
        const float w = __expf(-dsq / (2.f * sg * sg + 1e-8f));

        const float4 qrv = *reinterpret_cast<const float4*>(node_quat + (base_rt + (size_t)j) * 4);
        float rw = qrv.x, rx = qrv.y, ry = qrv.z, rz = qrv.w;
        {
            float inv = rsqrtf(fmaxf(rw * rw + rx * rx + ry * ry + rz * rz, 1e-24f));
            rw *= inv; rx *= inv; ry *= inv; rz *= inv;
        }
        const float4 qlv = *reinterpret_cast<const float4*>(node_quat + (base_t + (size_t)j) * 4);
        float lw = qlv.x, lx = qlv.y, ly = qlv.z, lz = qlv.w;
        {
            float inv = rsqrtf(fmaxf(lw * lw + lx * lx + ly * ly + lz * lz, 1e-24f));
            lw *= inv; lx *= inv; ly *= inv; lz *= inv;
        }
        const float qw =  lw * rw + lx * rx + ly * ry + lz * rz;
        const float qx = -lw * rx + lx * rw - ly * rz + lz * ry;
        const float qy = -lw * ry + lx * rz + ly * rw - lz * rx;
        const float qz = -lw * rz - lx * ry + ly * rx + lz * rw;

        float Rr[9];
        quat_to_R(qw, qx, qy, qz, Rr);

        const float* pl = node_xyz + (base_t + (size_t)j) * 3;
        const float m0 = Rr[0] * dx + Rr[1] * dy + Rr[2] * dz + pl[0];
        const float m1 = Rr[3] * dx + Rr[4] * dy + Rr[5] * dz + pl[1];
        const float m2 = Rr[6] * dx + Rr[7] * dy + Rr[8] * dz + pl[2];

        wsum += w;
        mu0 += w * m0; mu1 += w * m1; mu2 += w * m2;
        qb0 += w * qw; qb1 += w * qx; qb2 += w * qy; qb3 += w * qz;

        const float4* sp4 = reinterpret_cast<const float4*>(node_sem + (size_t)j * FSEM);
#pragma unroll
        for (int q = 0; q < 8; q++) {
            float4 v = sp4[q];
            sem[q * 4 + 0] += w * v.x;
            sem[q * 4 + 1] += w * v.y;
            sem[q * 4 + 2] += w * v.z;
            sem[q * 4 + 3] += w * v.w;
        }
    }

#pragma unroll
    for (int m = 1; m < LPG; m <<= 1) {
        wsum += __shfl_xor(wsum, m);
        mu0  += __shfl_xor(mu0, m);  mu1 += __shfl_xor(mu1, m);  mu2 += __shfl_xor(mu2, m);
        qb0  += __shfl_xor(qb0, m);  qb1 += __shfl_xor(qb1, m);
        qb2  += __shfl_xor(qb2, m);  qb3 += __shfl_xor(qb3, m);
#pragma unroll
        for (int f = 0; f < FSEM; f++) sem[f] += __shfl_xor(sem[f], m);
    }

    const float invw = 1.f / (wsum + 1e-8f);
    const size_t Ns = (size_t)N, ns = (size_t)n;

    if (sub == 0) {
        out[3 * ns + 0] = mu0 * invw;
        out[3 * ns + 1] = mu1 * invw;
        out[3 * ns + 2] = mu2 * invw;
    } else if (sub == 1) {
        // fr_live = q2R(qb*invw) @ (Rref @ q2R(gs_rot)). invw scaling BEFORE q2R
        // is required: unnormalized qb can denormalize in fp32 (r5 bug, 1.875).
        const float4 qg = *reinterpret_cast<const float4*>(gs_rot + 4 * ns);
        float Rg[9];
        quat_to_R(qg.x, qg.y, qg.z, qg.w, Rg);
        float Rw[9];
#pragma unroll
        for (int i = 0; i < 3; i++)
#pragma unroll
            for (int j = 0; j < 3; j++)
                Rw[3 * i + j] = Rref[3 * i] * Rg[j] + Rref[3 * i + 1] * Rg[3 + j] + Rref[3 * i + 2] * Rg[6 + j];
        float Rb[9];
        quat_to_R(qb0 * invw, qb1 * invw, qb2 * invw, qb3 * invw, Rb);
        float* ofr = out + 3 * Ns + 9 * ns;
#pragma unroll
        for (int i = 0; i < 3; i++)
#pragma unroll
            for (int j = 0; j < 3; j++)
                ofr[3 * i + j] = Rb[3 * i] * Rw[j] + Rb[3 * i + 1] * Rw[3 + j] + Rb[3 * i + 2] * Rw[6 + j];
    }

    // sem_live: [28N, 60N); each lane writes its 2 float4s
    float4* osem = reinterpret_cast<float4*>(out + 28 * Ns + FSEM * ns);
#pragma unroll
    for (int q = 0; q < 2; q++) {
        const int b = sub * 2 + q;
        osem[b] = make_float4(sem[4 * b + 0] * invw, sem[4 * b + 1] * invw,
                              sem[4 * b + 2] * invw, sem[4 * b + 3] * invw);
    }
}

extern "C" void kernel_launch(void* const* d_in, const int* in_sizes, int n_in,
                              void* d_out, int out_size, void* d_ws, size_t ws_size,
                              hipStream_t stream)
{
    const float* gs_xyz     = (const float*)d_in[0];
    const float* gs_rot     = (const float*)d_in[1];
    const float* gs_scal    = (const float*)d_in[2];
    const float* gs_opa     = (const float*)d_in[3];
    const float* feat_dc    = (const float*)d_in[4];
    const float* feat_rest  = (const float*)d_in[5];
    const float* node_xyz   = (const float*)d_in[6];
    const float* node_quat  = (const float*)d_in[7];
    const float* node_sigma = (const float*)d_in[8];
    const float* node_sem   = (const float*)d_in[9];
    const int* attach_ind   = (const int*)d_in[10];
    const int* ref_time     = (const int*)d_in[11];
    const int* topo_knn     = (const int*)d_in[12];
    const int* t_ptr        = (const int*)d_in[13];

    const int N = in_sizes[0] / 3;
    const int M = in_sizes[8];                 // node_sigma is (M,1)
    const int T = in_sizes[6] / (3 * M);       // node_xyz is (T,M,3)

    float* out = (float*)d_out;

    const size_t need = ((size_t)HDR + (size_t)N) * sizeof(int);
    const bool use_perm = (ws_size >= need) && (T <= 128);

    const int block = 256;
    const int gridN  = (N + block - 1) / block;
    const long long threads = (long long)N * LPG;
    const int gridM = (int)((threads + block - 1) / block);

    if (use_perm) {
        int* hdr  = (int*)d_ws;          // [0..T) counts/base, [128..128+T) cursor
        int* perm = hdr + HDR;

        hipLaunchKernelGGL(k_zero,    dim3(1),     dim3(HDR),  0, stream, hdr);
        hipLaunchKernelGGL(k_hist,    dim3(gridN), dim3(block), 0, stream, ref_time, hdr, N);
        hipLaunchKernelGGL(k_prefix,  dim3(1),     dim3(64),   0, stream, hdr, T);
        hipLaunchKernelGGL(k_scatter, dim3(gridN), dim3(block), 0, stream, ref_time, hdr, perm, N);
        hipLaunchKernelGGL((dynscf_kernel<true>), dim3(gridM), dim3(block), 0, stream,
                           gs_xyz, gs_rot, node_xyz, node_quat, node_sigma, node_sem,
                           attach_ind, ref_time, topo_knn, t_ptr, perm, out, N, M);
    } else {
        hipLaunchKernelGGL((dynscf_kernel<false>), dim3(gridM), dim3(block), 0, stream,
                           gs_xyz, gs_rot, node_xyz, node_quat, node_sigma, node_sem,
                           attach_ind, ref_time, topo_knn, t_ptr, (const int*)nullptr, out, N, M);
    }

    hipLaunchKernelGGL(k_elem, dim3(gridN), dim3(block), 0, stream,
                       gs_scal, gs_opa, feat_dc, feat_rest, out, N);
}

// Round 9
// 298.520 us; speedup vs baseline: 3.2176x; 3.2176x over previous
//
#include <hip/hip_runtime.h>

#define KNN 16
#define FSEM 32
#define LPG 4                 // 4 lanes cooperate per gaussian

__device__ __forceinline__ float sigmoidf_(float x) { return 1.0f / (1.0f + __expf(-x)); }

// q / clip(|q|,1e-12) -> row-major 3x3
__device__ __forceinline__ void quat_to_R(float qw, float qx, float qy, float qz, float* R) {
    float d = qw * qw + qx * qx + qy * qy + qz * qz;
    float inv = rsqrtf(fmaxf(d, 1e-24f));
    float w = qw * inv, x = qx * inv, y = qy * inv, z = qz * inv;
    R[0] = 1.f - 2.f * (y * y + z * z); R[1] = 2.f * (x * y - w * z); R[2] = 2.f * (x * z + w * y);
    R[3] = 2.f * (x * y + w * z); R[4] = 1.f - 2.f * (x * x + z * z); R[5] = 2.f * (y * z - w * x);
    R[6] = 2.f * (x * z - w * y); R[7] = 2.f * (y * z + w * x); R[8] = 1.f - 2.f * (x * x + y * y);
}

// ---- prepack: packed[p] = {x,y,z,pad, qw,qx,qy,qz}  (32 B, line-friendly) ----
__global__ void __launch_bounds__(256)
k_pack(const float* __restrict__ node_xyz, const float* __restrict__ node_quat,
       float* __restrict__ packed, int TM)
{
    int p = blockIdx.x * blockDim.x + threadIdx.x;
    if (p >= TM) return;
    const float* x = node_xyz + 3 * (size_t)p;
    float4 a = make_float4(x[0], x[1], x[2], 0.f);
    float4 q = reinterpret_cast<const float4*>(node_quat)[p];
    float4* dst = reinterpret_cast<float4*>(packed + 8 * (size_t)p);
    dst[0] = a;
    dst[1] = q;
}

// ---- elementwise outputs in natural (coalesced) order: s, o, sph ----
__global__ void __launch_bounds__(256)
k_elem(const float* __restrict__ gs_scal,
       const float* __restrict__ gs_opa,
       const float* __restrict__ feat_dc,
       const float* __restrict__ feat_rest,
       float* __restrict__ out, int N)
{
    const int n = blockIdx.x * blockDim.x + threadIdx.x;
    if (n >= N) return;
    const size_t Ns = (size_t)N, ns = (size_t)n;

    float* os = out + 12 * Ns + 3 * ns;
    os[0] = 0.1f * sigmoidf_(gs_scal[3 * ns + 0]);
    os[1] = 0.1f * sigmoidf_(gs_scal[3 * ns + 1]);
    os[2] = 0.1f * sigmoidf_(gs_scal[3 * ns + 2]);

    out[15 * Ns + ns] = sigmoidf_(gs_opa[ns]);

    float* osph = out + 16 * Ns + 12 * ns;   // 16B-aligned
    float4 v0 = make_float4(feat_dc[3 * ns + 0], feat_dc[3 * ns + 1], feat_dc[3 * ns + 2],
                            feat_rest[9 * ns + 0]);
    float4 v1 = make_float4(feat_rest[9 * ns + 1], feat_rest[9 * ns + 2],
                            feat_rest[9 * ns + 3], feat_rest[9 * ns + 4]);
    float4 v2 = make_float4(feat_rest[9 * ns + 5], feat_rest[9 * ns + 6],
                            feat_rest[9 * ns + 7], feat_rest[9 * ns + 8]);
    reinterpret_cast<float4*>(osph)[0] = v0;
    reinterpret_cast<float4*>(osph)[1] = v1;
    reinterpret_cast<float4*>(osph)[2] = v2;
}

// ---- main skinning kernel over packed (or raw) node data ----
template<bool PACKED>
__global__ void __launch_bounds__(256)
dynscf_kernel(const float* __restrict__ gs_xyz,
              const float* __restrict__ gs_rot,
              const float* __restrict__ node_xyz,
              const float* __restrict__ node_quat,
              const float* __restrict__ packed,
              const float* __restrict__ node_sigma,
              const float* __restrict__ node_sem,
              const int* __restrict__ attach_ind,
              const int* __restrict__ ref_time,
              const int* __restrict__ topo_knn,
              const int* __restrict__ t_ptr,
              float* __restrict__ out,
              int N, int M)
{
    const int tid = blockIdx.x * blockDim.x + threadIdx.x;
    const int n   = tid >> 2;
    const int sub = tid & (LPG - 1);
    if (n >= N) return;

    const int t  = t_ptr[0];
    const int a  = attach_ind[n];
    const int rt = ref_time[n];

    const size_t base_rt = (size_t)rt * (size_t)M;
    const size_t base_t  = (size_t)t  * (size_t)M;

    // --- attach node @ ref time ---
    float apx, apy, apz, aqw, aqx, aqy, aqz;
    if (PACKED) {
        const float4* pk = reinterpret_cast<const float4*>(packed + (base_rt + (size_t)a) * 8);
        float4 xz = pk[0], qv = pk[1];
        apx = xz.x; apy = xz.y; apz = xz.z;
        aqw = qv.x; aqx = qv.y; aqy = qv.z; aqz = qv.w;
    } else {
        const float4 qv = *reinterpret_cast<const float4*>(node_quat + (base_rt + (size_t)a) * 4);
        const float* pa = node_xyz + (base_rt + (size_t)a) * 3;
        apx = pa[0]; apy = pa[1]; apz = pa[2];
        aqw = qv.x; aqx = qv.y; aqy = qv.z; aqz = qv.w;
    }
    float Rref[9];
    quat_to_R(aqw, aqx, aqy, aqz, Rref);

    const float gx = gs_xyz[3 * (size_t)n + 0];
    const float gy = gs_xyz[3 * (size_t)n + 1];
    const float gz = gs_xyz[3 * (size_t)n + 2];

    const float xw0 = Rref[0] * gx + Rref[1] * gy + Rref[2] * gz + apx;
    const float xw1 = Rref[3] * gx + Rref[4] * gy + Rref[5] * gz + apy;
    const float xw2 = Rref[6] * gx + Rref[7] * gy + Rref[8] * gz + apz;

    const int4 kv = reinterpret_cast<const int4*>(topo_knn)[(size_t)a * (KNN / 4) + sub];
    const int js[4] = { kv.x, kv.y, kv.z, kv.w };

    float wsum = 0.f, mu0 = 0.f, mu1 = 0.f, mu2 = 0.f;
    float qb0 = 0.f, qb1 = 0.f, qb2 = 0.f, qb3 = 0.f;
    float sem[FSEM];
#pragma unroll
    for (int f = 0; f < FSEM; f++) sem[f] = 0.f;

#pragma unroll
    for (int k = 0; k < KNN / LPG; k++) {
        const int j = js[k];

        float prx, pry, prz, rw, rx, ry, rz;
        float plx, ply, plz, lw, lx, ly, lz;
        if (PACKED) {
            const float4* pkr = reinterpret_cast<const float4*>(packed + (base_rt + (size_t)j) * 8);
            float4 xr = pkr[0], qr = pkr[1];
            prx = xr.x; pry = xr.y; prz = xr.z;
            rw = qr.x; rx = qr.y; ry = qr.z; rz = qr.w;
            const float4* pkl = reinterpret_cast<const float4*>(packed + (base_t + (size_t)j) * 8);
            float4 xl = pkl[0], ql = pkl[1];
            plx = xl.x; ply = xl.y; plz = xl.z;
            lw = ql.x; lx = ql.y; ly = ql.z; lz = ql.w;
        } else {
            const float* pr = node_xyz + (base_rt + (size_t)j) * 3;
            prx = pr[0]; pry = pr[1]; prz = pr[2];
            const float4 qr = *reinterpret_cast<const float4*>(node_quat + (base_rt + (size_t)j) * 4);
            rw = qr.x; rx = qr.y; ry = qr.z; rz = qr.w;
            const float* pl = node_xyz + (base_t + (size_t)j) * 3;
            plx = pl[0]; ply = pl[1]; plz = pl[2];
            const float4 ql = *reinterpret_cast<const float4*>(node_quat + (base_t + (size_t)j) * 4);
            lw = ql.x; lx = ql.y; ly = ql.z; lz = ql.w;
        }

        const float dx = xw0 - prx;
        const float dy = xw1 - pry;
        const float dz = xw2 - prz;
        const float dsq = dx * dx + dy * dy + dz * dz;

        const float sg = node_sigma[j];
        const float w = __expf(-dsq / (2.f * sg * sg + 1e-8f));

        {
            float inv = rsqrtf(fmaxf(rw * rw + rx * rx + ry * ry + rz * rz, 1e-24f));
            rw *= inv; rx *= inv; ry *= inv; rz *= inv;
        }
        {
            float inv = rsqrtf(fmaxf(lw * lw + lx * lx + ly * ly + lz * lz, 1e-24f));
            lw *= inv; lx *= inv; ly *= inv; lz *= inv;
        }
        // q_rel = q_live * conj(q_ref)
        const float qw =  lw * rw + lx * rx + ly * ry + lz * rz;
        const float qx = -lw * rx + lx * rw - ly * rz + lz * ry;
        const float qy = -lw * ry + lx * rz + ly * rw - lz * rx;
        const float qz = -lw * rz - lx * ry + ly * rx + lz * rw;

        float Rr[9];
        quat_to_R(qw, qx, qy, qz, Rr);

        const float m0 = Rr[0] * dx + Rr[1] * dy + Rr[2] * dz + plx;
        const float m1 = Rr[3] * dx + Rr[4] * dy + Rr[5] * dz + ply;
        const float m2 = Rr[6] * dx + Rr[7] * dy + Rr[8] * dz + plz;

        wsum += w;
        mu0 += w * m0; mu1 += w * m1; mu2 += w * m2;
        qb0 += w * qw; qb1 += w * qx; qb2 += w * qy; qb3 += w * qz;

        const float4* sp4 = reinterpret_cast<const float4*>(node_sem + (size_t)j * FSEM);
#pragma unroll
        for (int q = 0; q < 8; q++) {
            float4 v = sp4[q];
            sem[q * 4 + 0] += w * v.x;
            sem[q * 4 + 1] += w * v.y;
            sem[q * 4 + 2] += w * v.z;
            sem[q * 4 + 3] += w * v.w;
        }
    }

#pragma unroll
    for (int m = 1; m < LPG; m <<= 1) {
        wsum += __shfl_xor(wsum, m);
        mu0  += __shfl_xor(mu0, m);  mu1 += __shfl_xor(mu1, m);  mu2 += __shfl_xor(mu2, m);
        qb0  += __shfl_xor(qb0, m);  qb1 += __shfl_xor(qb1, m);
        qb2  += __shfl_xor(qb2, m);  qb3 += __shfl_xor(qb3, m);
#pragma unroll
        for (int f = 0; f < FSEM; f++) sem[f] += __shfl_xor(sem[f], m);
    }

    const float invw = 1.f / (wsum + 1e-8f);
    const size_t Ns = (size_t)N, ns = (size_t)n;

    if (sub == 0) {
        out[3 * ns + 0] = mu0 * invw;
        out[3 * ns + 1] = mu1 * invw;
        out[3 * ns + 2] = mu2 * invw;
    } else if (sub == 1) {
        // fr_live = q2R(qb*invw) @ (Rref @ q2R(gs_rot)); invw BEFORE q2R (fp32
        // subnormal guard — r5 bug).
        const float4 qg = *reinterpret_cast<const float4*>(gs_rot + 4 * ns);
        float Rg[9];
        quat_to_R(qg.x, qg.y, qg.z, qg.w, Rg);
        float Rw[9];
#pragma unroll
        for (int i = 0; i < 3; i++)
#pragma unroll
            for (int j = 0; j < 3; j++)
                Rw[3 * i + j] = Rref[3 * i] * Rg[j] + Rref[3 * i + 1] * Rg[3 + j] + Rref[3 * i + 2] * Rg[6 + j];
        float Rb[9];
        quat_to_R(qb0 * invw, qb1 * invw, qb2 * invw, qb3 * invw, Rb);
        float* ofr = out + 3 * Ns + 9 * ns;
#pragma unroll
        for (int i = 0; i < 3; i++)
#pragma unroll
            for (int j = 0; j < 3; j++)
                ofr[3 * i + j] = Rb[3 * i] * Rw[j] + Rb[3 * i + 1] * Rw[3 + j] + Rb[3 * i + 2] * Rw[6 + j];
    }

    // sem_live: [28N, 60N); each lane writes its 2 float4s
    float4* osem = reinterpret_cast<float4*>(out + 28 * Ns + FSEM * ns);
#pragma unroll
    for (int q = 0; q < 2; q++) {
        const int b = sub * 2 + q;
        osem[b] = make_float4(sem[4 * b + 0] * invw, sem[4 * b + 1] * invw,
                              sem[4 * b + 2] * invw, sem[4 * b + 3] * invw);
    }
}

extern "C" void kernel_launch(void* const* d_in, const int* in_sizes, int n_in,
                              void* d_out, int out_size, void* d_ws, size_t ws_size,
                              hipStream_t stream)
{
    const float* gs_xyz     = (const float*)d_in[0];
    const float* gs_rot     = (const float*)d_in[1];
    const float* gs_scal    = (const float*)d_in[2];
    const float* gs_opa     = (const float*)d_in[3];
    const float* feat_dc    = (const float*)d_in[4];
    const float* feat_rest  = (const float*)d_in[5];
    const float* node_xyz   = (const float*)d_in[6];
    const float* node_quat  = (const float*)d_in[7];
    const float* node_sigma = (const float*)d_in[8];
    const float* node_sem   = (const float*)d_in[9];
    const int* attach_ind   = (const int*)d_in[10];
    const int* ref_time     = (const int*)d_in[11];
    const int* topo_knn     = (const int*)d_in[12];
    const int* t_ptr        = (const int*)d_in[13];

    const int N = in_sizes[0] / 3;
    const int M = in_sizes[8];                 // node_sigma is (M,1)
    const int TM = in_sizes[6] / 3;            // T*M

    float* out = (float*)d_out;

    const int block = 256;
    const int gridN = (N + block - 1) / block;
    const long long threads = (long long)N * LPG;
    const int gridM = (int)((threads + block - 1) / block);

    const size_t need = (size_t)TM * 8 * sizeof(float);   // 32 B per (t,node)
    const bool packed_ok = (ws_size >= need);

    if (packed_ok) {
        float* packed = (float*)d_ws;
        const int gridP = (TM + block - 1) / block;
        hipLaunchKernelGGL(k_pack, dim3(gridP), dim3(block), 0, stream,
                           node_xyz, node_quat, packed, TM);
        hipLaunchKernelGGL((dynscf_kernel<true>), dim3(gridM), dim3(block), 0, stream,
                           gs_xyz, gs_rot, node_xyz, node_quat, packed, node_sigma, node_sem,
                           attach_ind, ref_time, topo_knn, t_ptr, out, N, M);
    } else {
        hipLaunchKernelGGL((dynscf_kernel<false>), dim3(gridM), dim3(block), 0, stream,
                           gs_xyz, gs_rot, node_xyz, node_quat, (const float*)nullptr,
                           node_sigma, node_sem,
                           attach_ind, ref_time, topo_knn, t_ptr, out, N, M);
    }

    hipLaunchKernelGGL(k_elem, dim3(gridN), dim3(block), 0, stream,
                       gs_scal, gs_opa, feat_dc, feat_rest, out, N);
}